// Round 12
// baseline (254.166 us; speedup 1.0000x reference)
//
#include <hip/hip_runtime.h>

typedef unsigned short u16;
typedef __bf16 bf16x8 __attribute__((ext_vector_type(8)));
typedef float f32x4 __attribute__((ext_vector_type(4)));
typedef float f32x16 __attribute__((ext_vector_type(16)));

#define AS1 __attribute__((address_space(1)))
#define AS3 __attribute__((address_space(3)))

static __device__ __forceinline__ u16 f2bf(float f) {
  union { float f; unsigned u; } v; v.f = f;
  unsigned r = (v.u + 0x7fff + ((v.u >> 16) & 1)) >> 16;
  return (u16)r;
}

// x [B][258] f32 -> hx [B][256] bf16, phase [B] float2
__global__ void prep_x_kernel(const float* __restrict__ x, u16* __restrict__ hx,
                              float2* __restrict__ phase, int B) {
  int i = blockIdx.x * blockDim.x + threadIdx.x;
  int total = B * 128;
  if (i < total) {
    int row = i >> 7, k2 = (i & 127);
    const float2 v = *reinterpret_cast<const float2*>(x + (size_t)row * 258 + k2 * 2);
    u16 a = f2bf(v.x), b = f2bf(v.y);
    *reinterpret_cast<unsigned*>(hx + (size_t)row * 256 + k2 * 2) =
        (unsigned)a | ((unsigned)b << 16);
  }
  if (i < B) {
    phase[i] = *reinterpret_cast<const float2*>(x + (size_t)i * 258 + 256);
  }
}

// w [2][K][N] f32 -> wt [2][N][K] bf16 (plain transposed layout, for layer 3)
__global__ void prep_w_kernel(const float* __restrict__ w, u16* __restrict__ wt,
                              int K, int N) {
  __shared__ u16 tile[64][65];
  int k0 = blockIdx.x * 64, n0 = blockIdx.y * 64, mode = blockIdx.z;
  const float* src = w + (size_t)mode * K * N;
  u16* dst = wt + (size_t)mode * N * K;
  int c = threadIdx.x & 63;
  int r4 = threadIdx.x >> 6;
#pragma unroll
  for (int i = 0; i < 16; ++i) {
    int r = r4 + i * 4;
    tile[r][c] = f2bf(src[(size_t)(k0 + r) * N + n0 + c]);
  }
  __syncthreads();
#pragma unroll
  for (int i = 0; i < 16; ++i) {
    int r = r4 + i * 4;  // n index offset
    dst[(size_t)(n0 + r) * K + k0 + c] = tile[c][r];
  }
}

// w [2][K][N] f32 -> wt' [2N][K] bf16, mode-interleaved by 32-col groups:
// n' = (n>>5)*64 + mode*32 + (n&31)   (verified correct in R4)
__global__ void prep_w_int32_kernel(const float* __restrict__ w, u16* __restrict__ wt,
                                    int K, int N) {
  __shared__ u16 tile[64][65];
  int k0 = blockIdx.x * 64, n0 = blockIdx.y * 64, mode = blockIdx.z;
  const float* src = w + (size_t)mode * K * N;
  int c = threadIdx.x & 63;
  int r4 = threadIdx.x >> 6;
#pragma unroll
  for (int i = 0; i < 16; ++i) {
    int r = r4 + i * 4;
    tile[r][c] = f2bf(src[(size_t)(k0 + r) * N + n0 + c]);
  }
  __syncthreads();
#pragma unroll
  for (int i = 0; i < 16; ++i) {
    int n = n0 + r4 + i * 4;
    int np = ((n >> 5) << 6) + (mode << 5) + (n & 31);
    wt[(size_t)np * K + k0 + c] = tile[c][r4 + i * 4];
  }
}

// ---------------------------------------------------------------------------
// 256x256-tile ring-4 GEMM over N' = 2N (mode-interleaved by 32 cols),
// 32x32x16 MFMA with a swizzle DERIVED FOR THE 32x32 READ PATTERN:
//   slot s' = s ^ ((rl>>1)&3) within each 16-row x 64B subtile
// (R4's st_16x32 swizzle left rows r, r+2 aliased -> 8-way conflict; this
// one covers all 8 bank-groups across rows 0-7, rows 8-15 = free 2-way.)
// 8 waves (2M x 4N), wave tile 128x64 (4 mfrags x 2 nfrags of 32x32), BK=32,
// R5 schedule: 1 barrier/K-tile, counted vmcnt(8), R6-formalized tail drain.
// ---------------------------------------------------------------------------
template <bool ELU_STORE>
__global__ __launch_bounds__(512, 2) void gemm_ring32(
    const u16* __restrict__ A, const u16* __restrict__ Wt,
    const float* __restrict__ bias, const float2* __restrict__ phase,
    u16* __restrict__ out, int K, int Np) {
  __shared__ u16 lds[4][2][8192];  // [ring buf][A|B][256 rows x 32 cols swz]
  const int tnc = Np >> 8;  // 8
  const int nwg = gridDim.x;
  int id = blockIdx.x;
  const int cpx = nwg >> 3;  // nwg % 8 == 0 (1024)
  id = (id & 7) * cpx + (id >> 3);
  const int m0 = (id / tnc) * 256;
  const int n0 = (id % tnc) * 256;
  const int t = threadIdx.x;
  const int lane = t & 63;
  const int wave = t >> 6;
  const int wr = wave >> 2, wc = wave & 3;  // wave tile 128x64
  const int l31 = lane & 31, lhi = lane >> 5;
  const int rl = lane & 15;

  // 32x32 fragment read offsets (one per kk): lane reads 16B at
  // (row = frag*32 + l31, col = kk*16 + lhi*8):
  //   subtile (l31>>4), row-in-sub rl, slot s = kk*2 + lhi, swz s^=((rl>>1)&3)
  int cx32[2];
#pragma unroll
  for (int kk = 0; kk < 2; ++kk)
    cx32[kk] = ((l31 >> 4) << 10) + rl * 64 +
               ((((kk * 2 + lhi) ^ ((rl >> 1) & 3))) << 4);

  // staging decode: 16B chunk q = ld*512 + t at linear LDS byte e = q*16;
  // invert the swizzle on the global source column:
  int soff[2];
#pragma unroll
  for (int ld = 0; ld < 2; ++ld) {
    int e = (ld * 512 + t) * 16;
    int st = e >> 10, rr = (e >> 6) & 15, sp = (e >> 4) & 3;
    int s = sp ^ ((rr >> 1) & 3);
    soff[ld] = (st * 16 + rr) * K + s * 8;
  }
  const u16* Abase = A + (size_t)m0 * K;
  const u16* Bbase = Wt + (size_t)n0 * K;

  f32x16 acc[4][2] = {};
  const int NT = K >> 5;  // 8 (L1) or 32 (L2)

  auto stage = [&](int bb, int tile) {
    const int kt = tile << 5;
#pragma unroll
    for (int ld = 0; ld < 2; ++ld)
      __builtin_amdgcn_global_load_lds(
          (const AS1 void*)(Abase + kt + soff[ld]),
          (AS3 void*)(&lds[bb][0][(ld * 512 + t) * 8]), 16, 0, 0);
#pragma unroll
    for (int ld = 0; ld < 2; ++ld)
      __builtin_amdgcn_global_load_lds(
          (const AS1 void*)(Bbase + kt + soff[ld]),
          (AS3 void*)(&lds[bb][1][(ld * 512 + t) * 8]), 16, 0, 0);
  };

#define BAR()                    \
  asm volatile("" ::: "memory"); \
  __builtin_amdgcn_s_barrier();  \
  asm volatile("" ::: "memory");

  // A frag m (m=0..3): subtile base (wr*8 + m*2). B frag n: (wc*4 + n*2).
#define LOADA0(buf)                                                           \
  _Pragma("unroll") for (int m = 0; m < 2; ++m)                               \
  _Pragma("unroll") for (int kk = 0; kk < 2; ++kk)                            \
      af0[m][kk] = *(const bf16x8*)((const char*)&lds[buf][0][0] +            \
                                    ((wr * 8 + m * 2) << 10) + cx32[kk]);
#define LOADA1(buf)                                                           \
  _Pragma("unroll") for (int m = 0; m < 2; ++m)                               \
  _Pragma("unroll") for (int kk = 0; kk < 2; ++kk)                            \
      af1[m][kk] = *(const bf16x8*)((const char*)&lds[buf][0][0] +            \
                                    ((wr * 8 + (m + 2) * 2) << 10) + cx32[kk]);
#define LOADB(buf)                                                            \
  _Pragma("unroll") for (int n = 0; n < 2; ++n)                               \
  _Pragma("unroll") for (int kk = 0; kk < 2; ++kk)                            \
      bfr[n][kk] = *(const bf16x8*)((const char*)&lds[buf][1][0] +            \
                                    ((wc * 4 + n * 2) << 10) + cx32[kk]);
#define MFMAH(mh, AF)                                                         \
  __builtin_amdgcn_s_setprio(1);                                              \
  _Pragma("unroll") for (int m = 0; m < 2; ++m)                               \
  _Pragma("unroll") for (int n = 0; n < 2; ++n)                               \
  _Pragma("unroll") for (int kk = 0; kk < 2; ++kk)                            \
      acc[(mh)*2 + m][n] = __builtin_amdgcn_mfma_f32_32x32x16_bf16(           \
          AF[m][kk], bfr[n][kk], acc[(mh)*2 + m][n], 0, 0, 0);                \
  __builtin_amdgcn_s_setprio(0);

  bf16x8 af0[2][2], af1[2][2], bfr[2][2];

  // prologue: 3 tiles deep; vmcnt(8) retires tile 0's 4 loads; then BAR
  // (wait BEFORE barrier per R8 invariant).
  stage(0, 0);
  stage(1, 1);
  stage(2, 2);
  asm volatile("s_waitcnt vmcnt(8)" ::: "memory");
  BAR();
  LOADA0(0);
  LOADB(0);

  for (int tt = 0; tt < NT; ++tt) {
    const int b = tt & 3;
    // issue second-half A reads; they fly under MFMAH(0)
    LOADA1(b);
    MFMAH(0, af0);                  // consumes af0/bfr (issued pre-barrier)
    if (tt + 3 < NT) {
      stage((tt + 3) & 3, tt + 3);
      // outstanding: tiles tt+1, tt+2, tt+3 (12); retire tt+1's 4
      asm volatile("s_waitcnt vmcnt(8)" ::: "memory");
    } else {
      // tail (R6 lesson): no stage issued -> counted wait could no-op; drain.
      asm volatile("s_waitcnt vmcnt(0)" ::: "memory");
    }
    MFMAH(1, af1);                  // consumes af1 (overlapped with MFMAH(0))
    BAR();
    // issue next tile's first-half reads; they fly across the loop edge
    if (tt + 1 < NT) {
      const int b2 = (tt + 1) & 3;
      LOADA0(b2);
      LOADB(b2);
    }
  }
#undef LOADA0
#undef LOADA1
#undef LOADB
#undef MFMAH

  // epilogue (verified in R4): 32x32 C/D map col = lane&31,
  // row = (reg&3) + 8*(reg>>2) + 4*lhi. nfrag 0 = mode0, 1 = mode1, same cols.
  const int Nreal = Np >> 1;
  const int col = (n0 >> 1) + wc * 32 + l31;
  const float bias0 = bias[col];
  const float bias1 = bias[Nreal + col];
#pragma unroll
  for (int m = 0; m < 4; ++m) {
#pragma unroll
    for (int rg = 0; rg < 16; ++rg) {
      int grow = m0 + wr * 128 + m * 32 + (rg & 3) + 8 * (rg >> 2) + 4 * lhi;
      float2 ph = phase[grow];
      float v = ph.x * (acc[m][0][rg] + bias0) + ph.y * (acc[m][1][rg] + bias1);
      if (ELU_STORE) v = v > 0.f ? v : (__expf(v) - 1.f);
      out[(size_t)grow * Nreal + col] = f2bf(v);
    }
  }
#undef BAR
}

// Dual-mode GEMM (layer 3, small N): acc_i = A @ W_i^T, blended epilogue, f32 out
template <int BM, int BN, int WM, int WN, bool ELU_BF16>
__launch_bounds__(256, 2) __global__
void gemm_dualmode(const u16* __restrict__ A, const u16* __restrict__ WT,
                   const float* __restrict__ bias, const float2* __restrict__ phase,
                   void* __restrict__ out, int K, int N) {
  constexpr int MF = WM / 16, NF = WN / 16;
  __shared__ u16 ldsA[BM * 32];
  __shared__ u16 ldsB[2][BN * 32];
  const int m0 = blockIdx.x * BM;
  const int n0 = blockIdx.y * BN;
  const int t = threadIdx.x;
  const int wave = t >> 6, lane = t & 63;
  constexpr int NWC = BN / WN;
  const int wr = wave / NWC, wc = wave % NWC;
  const int lr = lane & 15, ks = lane >> 4;

  f32x4 acc[2][MF][NF] = {};

  for (int kt = 0; kt < K; kt += 32) {
#pragma unroll
    for (int i = 0; i < BM / 64; ++i) {
      int tt = t + i * 256;
      int r = tt >> 2, c8 = (tt & 3) * 8;
      __builtin_amdgcn_global_load_lds(
          (const AS1 void*)(A + (size_t)(m0 + r) * K + kt + c8),
          (AS3 void*)(ldsA + (size_t)tt * 8), 16, 0, 0);
    }
#pragma unroll
    for (int md = 0; md < 2; ++md) {
#pragma unroll
      for (int i = 0; i < BN / 64; ++i) {
        int tt = t + i * 256;
        int r = tt >> 2, c8 = (tt & 3) * 8;
        __builtin_amdgcn_global_load_lds(
            (const AS1 void*)(WT + (size_t)md * N * K + (size_t)(n0 + r) * K + kt + c8),
            (AS3 void*)(ldsB[md] + (size_t)tt * 8), 16, 0, 0);
      }
    }
    __syncthreads();

    bf16x8 af[MF], b0f[NF], b1f[NF];
#pragma unroll
    for (int m = 0; m < MF; ++m)
      af[m] = *reinterpret_cast<const bf16x8*>(&ldsA[(wr * WM + m * 16 + lr) * 32 + ks * 8]);
#pragma unroll
    for (int n = 0; n < NF; ++n) {
      b0f[n] = *reinterpret_cast<const bf16x8*>(&ldsB[0][(wc * WN + n * 16 + lr) * 32 + ks * 8]);
      b1f[n] = *reinterpret_cast<const bf16x8*>(&ldsB[1][(wc * WN + n * 16 + lr) * 32 + ks * 8]);
    }
#pragma unroll
    for (int m = 0; m < MF; ++m) {
#pragma unroll
      for (int n = 0; n < NF; ++n) {
        acc[0][m][n] = __builtin_amdgcn_mfma_f32_16x16x32_bf16(af[m], b0f[n], acc[0][m][n], 0, 0, 0);
        acc[1][m][n] = __builtin_amdgcn_mfma_f32_16x16x32_bf16(af[m], b1f[n], acc[1][m][n], 0, 0, 0);
      }
    }
    __syncthreads();
  }

#pragma unroll
  for (int m = 0; m < MF; ++m) {
#pragma unroll
    for (int j = 0; j < 4; ++j) {
      int grow = m0 + wr * WM + m * 16 + ks * 4 + j;
      float2 ph = phase[grow];
#pragma unroll
      for (int n = 0; n < NF; ++n) {
        int gcol = n0 + wc * WN + n * 16 + lr;
        float v = ph.x * (acc[0][m][n][j] + bias[gcol]) +
                  ph.y * (acc[1][m][n][j] + bias[N + gcol]);
        if (ELU_BF16) {
          v = v > 0.f ? v : (__expf(v) - 1.f);
          ((u16*)out)[(size_t)grow * N + gcol] = f2bf(v);
        } else {
          ((float*)out)[(size_t)grow * N + gcol] = v;
        }
      }
    }
  }
}

extern "C" void kernel_launch(void* const* d_in, const int* in_sizes, int n_in,
                              void* d_out, int out_size, void* d_ws, size_t ws_size,
                              hipStream_t stream) {
  const float* x  = (const float*)d_in[0];
  const float* w1 = (const float*)d_in[1];
  const float* b1 = (const float*)d_in[2];
  const float* w2 = (const float*)d_in[3];
  const float* b2 = (const float*)d_in[4];
  const float* w3 = (const float*)d_in[5];
  const float* b3 = (const float*)d_in[6];
  float* out = (float*)d_out;
  const int B = 32768, DIN = 256, H = 1024, DOUT = 64;

  char* ws = (char*)d_ws;
  u16* W1Ti = (u16*)ws;    ws += (size_t)2 * H * DIN * 2;   // [2048][256]
  u16* W2Ti = (u16*)ws;    ws += (size_t)2 * H * H * 2;     // [2048][1024]
  u16* W3T = (u16*)ws;     ws += (size_t)2 * DOUT * H * 2;  // [2][64][1024]
  float2* phase = (float2*)ws; ws += (size_t)B * 8;
  u16* hx = (u16*)ws;      ws += (size_t)B * DIN * 2;
  u16* h1 = (u16*)ws;      ws += (size_t)B * H * 2;
  u16* h2 = (u16*)ws;      ws += (size_t)B * H * 2;

  prep_x_kernel<<<(B * 128 + 255) / 256, 256, 0, stream>>>(x, hx, phase, B);
  prep_w_int32_kernel<<<dim3(DIN / 64, H / 64, 2), 256, 0, stream>>>(w1, W1Ti, DIN, H);
  prep_w_int32_kernel<<<dim3(H / 64, H / 64, 2), 256, 0, stream>>>(w2, W2Ti, H, H);
  prep_w_kernel<<<dim3(H / 64, DOUT / 64, 2), 256, 0, stream>>>(w3, W3T, H, DOUT);

  const int nwg = (B / 256) * (2 * H / 256);  // 128 * 8 = 1024
  gemm_ring32<true><<<nwg, 512, 0, stream>>>(hx, W1Ti, b1, phase, h1, DIN, 2 * H);
  gemm_ring32<true><<<nwg, 512, 0, stream>>>(h1, W2Ti, b2, phase, h2, H, 2 * H);
  gemm_dualmode<128, 64, 64, 32, false>
      <<<dim3(B / 128, DOUT / 64), 256, 0, stream>>>(h2, W3T, b3, phase, out, H, DOUT);
}